// Round 4
// baseline (327.825 us; speedup 1.0000x reference)
//
#include <hip/hip_runtime.h>
#include <hip/hip_fp16.h>

// NNConv on MI355X. msg[E x 32] = Z[E x 4096] @ w2r[4096 x 32],
// Z[e, c*32+i] = h[e,c]*xs[e,i] built on the fly in fp16 A-fragments via
// v_pk_mul_f16.
// Round 14: ATOMIC-FREE aggregation. R11 vs R13 plateaued at ~135 us with
// totally different compute geometry; WRITE_SIZE == 12.8M x 4B exactly =>
// every device-scope float atomicAdd is an individual L2->fabric
// transaction (~39/cy chip-wide = the plateau). Replace scatter-atomics:
//   prep(pack+zero deg) -> hist -> scan -> fill (CSR, 0.8M int atomics)
//   -> edge kernel STORES dense msg[E][32] (coalesced, fire-and-forget)
//   -> final kernel gathers per-node edge lists + x@root + bias.
// Compute core unchanged from R13 (4 groups/wave, 4-deep B reg dbuf,
// barrier-free). Falls back to replica-atomic path if ws too small.

#define NN 25000
#define EE 400000

typedef _Float16 f16x8 __attribute__((ext_vector_type(8)));
typedef float    f32x16 __attribute__((ext_vector_type(16)));

// ---------------- prep: pack w1/w2/b2 to fp16 fragment layout + zero region ----------------
__global__ __launch_bounds__(256) void prep_kernel(
    const float* __restrict__ w1, const float* __restrict__ w2,
    const float* __restrict__ b2,
    _Float16* __restrict__ w2p, _Float16* __restrict__ w1p, _Float16* __restrict__ b2p,
    float4* __restrict__ zero4, int nzero4)
{
    int b = blockIdx.x;
    if (b < 532) {                       // 532*256 = 136192 pack threads, exact
        int t = b * 256 + threadIdx.x;
        if (t < 131072) {
            int j = t & 7, lane = (t >> 3) & 63, ih = (t >> 9) & 1, c = t >> 10;
            w2p[t] = (_Float16)w2[c * 1024 + (ih * 16 + ((lane >> 5) << 3) + j) * 32 + (lane & 31)];
        } else if (t < 135168) {
            int u = t - 131072;
            int j = u & 7, lane = (u >> 3) & 63, kk = (u >> 9) & 1, r = u >> 10;
            w1p[u] = (_Float16)w1[(kk * 16 + ((lane >> 5) << 3) + j) * 128 + r * 32 + (lane & 31)];
        } else {
            int u = t - 135168;
            int j = u & 7, lane = (u >> 3) & 63, ih = u >> 9;
            b2p[u] = (_Float16)b2[(ih * 16 + ((lane >> 5) << 3) + j) * 32 + (lane & 31)];
        }
    } else {
        int z = (b - 532) * 256 + threadIdx.x;
        if (z < nzero4) zero4[z] = make_float4(0.f, 0.f, 0.f, 0.f);
    }
}

// ---------------- CSR build ----------------
__global__ __launch_bounds__(256) void hist_kernel(const int* __restrict__ ei,
                                                   int* __restrict__ deg)
{
    int e = blockIdx.x * 256 + threadIdx.x;
    if (e < EE) atomicAdd(&deg[ei[EE + e]], 1);
}

// one block, 1024 threads: exclusive scan of deg[25000] -> rowptr[25001], copy -> cur
__global__ __launch_bounds__(1024) void scan_kernel(const int* __restrict__ deg,
                                                    int* __restrict__ rowptr,
                                                    int* __restrict__ cur)
{
    __shared__ int part[1024];
    const int t = threadIdx.x;
    const int base = t * 25;                 // 1024*25 = 25600 >= 25000
    const int cnt = (base < NN) ? ((NN - base < 25) ? (NN - base) : 25) : 0;
    int s = 0;
    for (int k = 0; k < cnt; ++k) s += deg[base + k];
    part[t] = s;
    __syncthreads();
    for (int off = 1; off < 1024; off <<= 1) {
        int v = (t >= off) ? part[t - off] : 0;
        __syncthreads();
        part[t] += v;
        __syncthreads();
    }
    int excl = (t == 0) ? 0 : part[t - 1];
    for (int k = 0; k < cnt; ++k) {
        int d = deg[base + k];
        rowptr[base + k] = excl;
        cur[base + k]    = excl;
        excl += d;
    }
    if (t == 1023) rowptr[NN] = part[1023];
}

__global__ __launch_bounds__(256) void fill_kernel(const int* __restrict__ ei,
                                                   int* __restrict__ cur,
                                                   int* __restrict__ eidx)
{
    int e = blockIdx.x * 256 + threadIdx.x;
    if (e < EE) {
        int pos = atomicAdd(&cur[ei[EE + e]], 1);
        eidx[pos] = e;
    }
}

// ---------------- final (gather mode): out = x@root + bias + sum over CSR edges ----------------
__global__ __launch_bounds__(256) void final_gather(
    const float* __restrict__ x, const float* __restrict__ root,
    const float* __restrict__ bias, const float* __restrict__ msg,
    const int* __restrict__ rowptr, const int* __restrict__ eidx,
    float* __restrict__ out)
{
    int gid = blockIdx.x * 256 + threadIdx.x;   // exactly NN*32
    int n = gid >> 5, o = gid & 31;
    float acc = bias[o];
    const float* xr = x + (n << 5);
#pragma unroll
    for (int i = 0; i < 32; ++i)
        acc = fmaf(xr[i], root[(i << 5) + o], acc);
    int k0 = rowptr[n], k1 = rowptr[n + 1];
    for (int k = k0; k < k1; ++k)
        acc += msg[(size_t)eidx[k] * 32 + o];
    out[gid] = acc;
}

// ---------------- final (replica fallback): out = x@root + bias + sum(replicas) ----------------
__global__ __launch_bounds__(256) void final_kernel(
    const float* __restrict__ x, const float* __restrict__ root,
    const float* __restrict__ bias, const float* __restrict__ part,
    int ncopies, float* __restrict__ out)
{
    int gid = blockIdx.x * 256 + threadIdx.x;   // exactly NN*32
    int n = gid >> 5, o = gid & 31;
    float acc = bias[o];
    const float* xr = x + (n << 5);
#pragma unroll
    for (int i = 0; i < 32; ++i)
        acc = fmaf(xr[i], root[(i << 5) + o], acc);
    for (int c = 0; c < ncopies; ++c) acc += part[(size_t)c * 800000 + gid];
    out[gid] = acc;
}

// ---------------- fused MFMA edge kernel (barrier-free, 4 groups/wave) ----------------
// 128 thr = 2 waves x 128 edges (4 groups of 32) = 256 edges/block, 1563 blocks.
// useStore != 0: write dense msg rows (no atomics). else: atomicAdd replicas.
__global__ __launch_bounds__(128, 2) void edge_kernel(
    const float*    __restrict__ x,
    const int*      __restrict__ ei,
    const float*    __restrict__ ea,
    const float*    __restrict__ b1,
    const _Float16* __restrict__ w2p,
    const _Float16* __restrict__ w1p,
    const _Float16* __restrict__ b2p,
    float* __restrict__ outp, int copyMask, int useStore)
{
    __shared__ unsigned short hTq[2][32][32][4];   // 16 KB: [wave][c_in_slice][l][g]

    const int t    = threadIdx.x;
    const int w    = t >> 6;
    const int lane = t & 63;
    const int l    = lane & 31;
    const int half = lane >> 5;

    const int  ebraw = blockIdx.x * 256 + w * 128;
    const bool live  = (ebraw + 128) <= EE;        // wave-uniform; 128 | EE
    const int  ebw   = live ? ebraw : (EE - 128);

    float* __restrict__ myout = outp + (size_t)(blockIdx.x & copyMask) * 800000;

    union u8h { f16x8 v; __half2 h2[4]; };

    // ---- w2 B-columns read DIRECTLY from global (L2-resident, 256 KB) ----
    const f16x8* __restrict__ w2f = (const f16x8*)w2p;

    f16x8 BA[2], BB[2], BC[2], BD[2];              // 4-deep column buffers
    auto loadCol = [&](int j, f16x8 (&B)[2]) {
        const f16x8* p = w2f + (size_t)j * 128 + lane;
        B[0] = p[0];
        B[1] = p[64];
    };
    loadCol(0, BA);                    // get loads flying before reg setup
    loadCol(1, BB);
    loadCol(2, BC);
    loadCol(3, BD);

    // ---- persistent edge-attr fragments (fp16), 4 groups; read ONCE (32 VGPR) ----
    u8h eaf[4][2];
#pragma unroll
    for (int g = 0; g < 4; ++g)
#pragma unroll
        for (int kk = 0; kk < 2; ++kk) {
            const float* p = ea + (size_t)(ebw + g * 32 + l) * 32 + kk * 16 + half * 8;
            float4 a0 = *(const float4*)p;
            float4 a1 = *(const float4*)(p + 4);
            eaf[g][kk].h2[0] = __float22half2_rn(make_float2(a0.x, a0.y));
            eaf[g][kk].h2[1] = __float22half2_rn(make_float2(a0.z, a0.w));
            eaf[g][kk].h2[2] = __float22half2_rn(make_float2(a1.x, a1.y));
            eaf[g][kk].h2[3] = __float22half2_rn(make_float2(a1.z, a1.w));
        }

    // ---- gather xs rows (fp16 pairs) for 4 groups: 32 VGPRs ----
    __half2 xs[4][8];
#pragma unroll
    for (int g = 0; g < 4; ++g) {
        int s = ei[ebw + g * 32 + l];
#pragma unroll
        for (int ih = 0; ih < 2; ++ih) {
            float4 a0 = *(const float4*)(x + s * 32 + ih * 16 + half * 8);
            float4 a1 = *(const float4*)(x + s * 32 + ih * 16 + half * 8 + 4);
            xs[g][ih*4+0] = __float22half2_rn(make_float2(a0.x, a0.y));
            xs[g][ih*4+1] = __float22half2_rn(make_float2(a0.z, a0.w));
            xs[g][ih*4+2] = __float22half2_rn(make_float2(a1.x, a1.y));
            xs[g][ih*4+3] = __float22half2_rn(make_float2(a1.z, a1.w));
        }
    }

    f32x16 acc[4];
#pragma unroll
    for (int g = 0; g < 4; ++g)
#pragma unroll
        for (int i = 0; i < 16; ++i) acc[g][i] = 0.f;

    // ---- phase-1 slice for r: all 32 rows of hT for 4 groups into LDS ----
    auto phase1 = [&](int r) {
        f16x8 w1f0 = *(const f16x8*)(w1p + ((r * 2 + 0) * 64 + lane) * 8);
        f16x8 w1f1 = *(const f16x8*)(w1p + ((r * 2 + 1) * 64 + lane) * 8);
#pragma unroll
        for (int g = 0; g < 4; ++g) {
            f32x16 h;
#pragma unroll
            for (int i = 0; i < 16; ++i) h[i] = 0.f;
            h = __builtin_amdgcn_mfma_f32_32x32x16_f16(w1f0, eaf[g][0].v, h, 0, 0, 0);
            h = __builtin_amdgcn_mfma_f32_32x32x16_f16(w1f1, eaf[g][1].v, h, 0, 0, 0);
#pragma unroll
            for (int i = 0; i < 16; ++i) {
                int row = (i & 3) + ((i >> 2) << 3) + (half << 2);   // verified C/D map
                float hv = fmaxf(h[i] + b1[r * 32 + row], 0.f);
                hTq[w][row][l][g] = __half_as_ushort(__float2half(hv));
            }
        }
    };

    // compute one c-column (8 MFMAs: 2 ih x 4 g) from register fragments
    auto computeCol = [&](int cs, const f16x8 (&B)[2]) {
        uint2 u = *(const uint2*)&hTq[w][cs][l][0];
        __half2 ha = *reinterpret_cast<const __half2*>(&u.x);
        __half2 hb = *reinterpret_cast<const __half2*>(&u.y);
        __half2 d[4];
        d[0] = __half2half2(__low2half(ha));
        d[1] = __half2half2(__high2half(ha));
        d[2] = __half2half2(__low2half(hb));
        d[3] = __half2half2(__high2half(hb));
#pragma unroll
        for (int ih = 0; ih < 2; ++ih) {
            f16x8 bfr = B[ih];
#pragma unroll
            for (int g = 0; g < 4; ++g) {
                u8h A;
#pragma unroll
                for (int p = 0; p < 4; ++p)
                    A.h2[p] = __hmul2(d[g], xs[g][ih * 4 + p]);   // v_pk_mul_f16
                acc[g] = __builtin_amdgcn_mfma_f32_32x32x16_f16(A.v, bfr, acc[g], 0, 0, 0);
            }
        }
    };

    // ---- pipeline: no barriers; 3-col prefetch distance via 4 buffers.
    // Max overread: col 131 -> bytes < 269312, lands in w1p/b2p workspace
    // region (valid memory, values unused). ----
#pragma unroll 1
    for (int r = 0; r < 4; ++r) {
        phase1(r);                     // wave-private hTq: no barrier needed
#pragma unroll 1
        for (int q = 0; q < 8; ++q) {
            const int j = r * 32 + q * 4;
            computeCol(q * 4 + 0, BA); loadCol(j + 4, BA);
            computeCol(q * 4 + 1, BB); loadCol(j + 5, BB);
            computeCol(q * 4 + 2, BC); loadCol(j + 6, BC);
            computeCol(q * 4 + 3, BD); loadCol(j + 7, BD);
        }
    }

    // ---- b2 contribution: extra K-step with h == 1 (A-fragment = xs, no VALU) ----
#pragma unroll
    for (int ih = 0; ih < 2; ++ih) {
        f16x8 bfr = *(const f16x8*)(b2p + (ih * 64 + lane) * 8);
#pragma unroll
        for (int g = 0; g < 4; ++g) {
            u8h A;
#pragma unroll
            for (int p = 0; p < 4; ++p) A.h2[p] = xs[g][ih * 4 + p];
            acc[g] = __builtin_amdgcn_mfma_f32_32x32x16_f16(A.v, bfr, acc[g], 0, 0, 0);
        }
    }

    // ---- output (skip for clamped tail waves) ----
    if (live) {
        if (useStore) {
            // dense msg rows: lanes 0..31 write 128 B contiguous per (g,i)
#pragma unroll
            for (int g = 0; g < 4; ++g)
#pragma unroll
                for (int i = 0; i < 16; ++i) {
                    int el = (i & 3) + ((i >> 2) << 3) + (half << 2);
                    myout[(size_t)(ebw + g * 32 + el) * 32 + l] = acc[g][i];
                }
        } else {
#pragma unroll
            for (int g = 0; g < 4; ++g)
#pragma unroll
                for (int i = 0; i < 16; ++i) {
                    int el = (i & 3) + ((i >> 2) << 3) + (half << 2);
                    atomicAdd(myout + ei[EE + ebw + g * 32 + el] * 32 + l, acc[g][i]);
                }
        }
    }
}

extern "C" void kernel_launch(void* const* d_in, const int* in_sizes, int n_in,
                              void* d_out, int out_size, void* d_ws, size_t ws_size,
                              hipStream_t stream) {
    const float* x    = (const float*)d_in[0];
    const int*   ei   = (const int*)  d_in[1];
    const float* ea   = (const float*)d_in[2];
    const float* w1   = (const float*)d_in[3];
    const float* b1   = (const float*)d_in[4];
    const float* w2   = (const float*)d_in[5];
    const float* b2   = (const float*)d_in[6];
    const float* root = (const float*)d_in[7];
    const float* bias = (const float*)d_in[8];
    float* out = (float*)d_out;

    _Float16* w2p = (_Float16*)d_ws;                      // 262144 B
    _Float16* w1p = (_Float16*)((char*)d_ws + 262144);    //   8192 B
    _Float16* b2p = (_Float16*)((char*)d_ws + 270336);    //   2048 B

    // CSR/store-mode layout (all 16B-aligned offsets)
    const size_t degOff  = 272384;                        // 25000 int  = 100000 B
    const size_t rowOff  = 372384;                        // 25001 int -> pad 100016 B
    const size_t curOff  = 472400;                        // 25000 int  = 100000 B
    const size_t eidxOff = 572400;                        // 400000 int = 1600000 B
    const size_t msgOff  = 2172400;                       // EE*32*4    = 51200000 B
    const size_t needStore = msgOff + (size_t)EE * 32 * 4;

    if (ws_size >= needStore) {
        int*   deg    = (int*)((char*)d_ws + degOff);
        int*   rowptr = (int*)((char*)d_ws + rowOff);
        int*   cur    = (int*)((char*)d_ws + curOff);
        int*   eidx   = (int*)((char*)d_ws + eidxOff);
        float* msg    = (float*)((char*)d_ws + msgOff);

        int nzero4 = 25000 / 4;                           // deg as float4 zeros
        int zb = (nzero4 + 255) / 256;
        prep_kernel<<<532 + zb, 256, 0, stream>>>(w1, w2, b2, w2p, w1p, b2p,
                                                  (float4*)deg, nzero4);
        hist_kernel<<<(EE + 255) / 256, 256, 0, stream>>>(ei, deg);
        scan_kernel<<<1, 1024, 0, stream>>>(deg, rowptr, cur);
        fill_kernel<<<(EE + 255) / 256, 256, 0, stream>>>(ei, cur, eidx);
        edge_kernel<<<(EE + 255) / 256, 128, 0, stream>>>(x, ei, ea, b1, w2p, w1p, b2p,
                                                          msg, 0, 1);
        final_gather<<<(NN * 32) / 256, 256, 0, stream>>>(x, root, bias, msg,
                                                          rowptr, eidx, out);
        return;
    }

    // ---- fallback: replica-atomic path (R13) ----
    const size_t partOff = 272384;
    const size_t one = 800000ull * sizeof(float);         // 3.2 MB per replica
    size_t avail = (ws_size > partOff) ? ws_size - partOff : 0;
    int nc = 0;
    for (int c = 8; c >= 1; c >>= 1)
        if ((size_t)c * one <= avail) { nc = c; break; }

    float* part = (float*)((char*)d_ws + partOff);
    if (nc > 0) {
        int nzero4 = nc * 200000;                         // float4 count
        int zb = (nzero4 + 255) / 256;
        prep_kernel<<<532 + zb, 256, 0, stream>>>(w1, w2, b2, w2p, w1p, b2p,
                                                  (float4*)part, nzero4);
        edge_kernel<<<(EE + 255) / 256, 128, 0, stream>>>(x, ei, ea, b1, w2p, w1p, b2p,
                                                          part, nc - 1, 0);
        final_kernel<<<(NN * 32) / 256, 256, 0, stream>>>(x, root, bias, part, nc, out);
    } else {
        prep_kernel<<<532, 256, 0, stream>>>(w1, w2, b2, w2p, w1p, b2p, (float4*)part, 0);
        final_kernel<<<(NN * 32) / 256, 256, 0, stream>>>(x, root, bias, part, 0, out);
        edge_kernel<<<(EE + 255) / 256, 128, 0, stream>>>(x, ei, ea, b1, w2p, w1p, b2p,
                                                          out, 0, 0);
    }
}

// Round 5
// 235.380 us; speedup vs baseline: 1.3927x; 1.3927x over previous
//
#include <hip/hip_runtime.h>
#include <hip/hip_fp16.h>
#include <hip/hip_cooperative_groups.h>

// NNConv on MI355X. msg[E x 32] = Z[E x 4096] @ w2r[4096 x 32],
// Z[e, c*32+i] = h[e,c]*xs[e,i] built on the fly in fp16 A-fragments via
// v_pk_mul_f16.
// Round 15: ONE cooperative launch. Cross-round fit shows ~28 us of dead
// time PER KERNEL LAUNCH in the measured window (R10/11/13: 3 launches ->
// ~85 us overhead; R14: 6 launches -> ~170+). That dwarfs every compute
// delta since R10. Fuse: phase A = pack w2/w1/b2 + out = x@root + bias
// (kills prep + final + replicas + zeroing; ws use = 272 KB);
// grid.sync(); phase B = R13 edge core, atomicAdd straight into out
// (+12 us vs store, known from R13-vs-R14). __launch_bounds__(128,4)
// forces VGPR<=128 -> 8 blocks/CU -> 1563 co-resident guaranteed; host
// verifies with occupancy query and falls back to the R13 3-launch path
// if cooperative launch is unavailable.

#define NN 25000
#define EE 400000

namespace cg = cooperative_groups;

typedef _Float16 f16x8 __attribute__((ext_vector_type(8)));
typedef float    f32x16 __attribute__((ext_vector_type(16)));

// ==================== fallback kernels (R13 path) ====================

__global__ __launch_bounds__(256) void prep_kernel(
    const float* __restrict__ w1, const float* __restrict__ w2,
    const float* __restrict__ b2,
    _Float16* __restrict__ w2p, _Float16* __restrict__ w1p, _Float16* __restrict__ b2p,
    float4* __restrict__ zero4, int nzero4)
{
    int b = blockIdx.x;
    if (b < 532) {
        int t = b * 256 + threadIdx.x;
        if (t < 131072) {
            int j = t & 7, lane = (t >> 3) & 63, ih = (t >> 9) & 1, c = t >> 10;
            w2p[t] = (_Float16)w2[c * 1024 + (ih * 16 + ((lane >> 5) << 3) + j) * 32 + (lane & 31)];
        } else if (t < 135168) {
            int u = t - 131072;
            int j = u & 7, lane = (u >> 3) & 63, kk = (u >> 9) & 1, r = u >> 10;
            w1p[u] = (_Float16)w1[(kk * 16 + ((lane >> 5) << 3) + j) * 128 + r * 32 + (lane & 31)];
        } else {
            int u = t - 135168;
            int j = u & 7, lane = (u >> 3) & 63, ih = u >> 9;
            b2p[u] = (_Float16)b2[(ih * 16 + ((lane >> 5) << 3) + j) * 32 + (lane & 31)];
        }
    } else {
        int z = (b - 532) * 256 + threadIdx.x;
        if (z < nzero4) zero4[z] = make_float4(0.f, 0.f, 0.f, 0.f);
    }
}

__global__ __launch_bounds__(256) void final_kernel(
    const float* __restrict__ x, const float* __restrict__ root,
    const float* __restrict__ bias, const float* __restrict__ part,
    int ncopies, float* __restrict__ out)
{
    int gid = blockIdx.x * 256 + threadIdx.x;
    int n = gid >> 5, o = gid & 31;
    float acc = bias[o];
    const float* xr = x + (n << 5);
#pragma unroll
    for (int i = 0; i < 32; ++i)
        acc = fmaf(xr[i], root[(i << 5) + o], acc);
    for (int c = 0; c < ncopies; ++c) acc += part[(size_t)c * 800000 + gid];
    out[gid] = acc;
}

__global__ __launch_bounds__(128, 2) void edge_kernel(
    const float*    __restrict__ x,
    const int*      __restrict__ ei,
    const float*    __restrict__ ea,
    const float*    __restrict__ b1,
    const _Float16* __restrict__ w2p,
    const _Float16* __restrict__ w1p,
    const _Float16* __restrict__ b2p,
    float* __restrict__ outp, int copyMask)
{
    __shared__ unsigned short hTq[2][32][32][4];

    const int t    = threadIdx.x;
    const int w    = t >> 6;
    const int lane = t & 63;
    const int l    = lane & 31;
    const int half = lane >> 5;

    const int  ebraw = blockIdx.x * 256 + w * 128;
    const bool live  = (ebraw + 128) <= EE;
    const int  ebw   = live ? ebraw : (EE - 128);

    float* __restrict__ myout = outp + (size_t)(blockIdx.x & copyMask) * 800000;

    union u8h { f16x8 v; __half2 h2[4]; };

    const f16x8* __restrict__ w2f = (const f16x8*)w2p;

    f16x8 BA[2], BB[2], BC[2], BD[2];
    auto loadCol = [&](int j, f16x8 (&B)[2]) {
        const f16x8* p = w2f + (size_t)j * 128 + lane;
        B[0] = p[0];
        B[1] = p[64];
    };
    loadCol(0, BA); loadCol(1, BB); loadCol(2, BC); loadCol(3, BD);

    u8h eaf[4][2];
#pragma unroll
    for (int g = 0; g < 4; ++g)
#pragma unroll
        for (int kk = 0; kk < 2; ++kk) {
            const float* p = ea + (size_t)(ebw + g * 32 + l) * 32 + kk * 16 + half * 8;
            float4 a0 = *(const float4*)p;
            float4 a1 = *(const float4*)(p + 4);
            eaf[g][kk].h2[0] = __float22half2_rn(make_float2(a0.x, a0.y));
            eaf[g][kk].h2[1] = __float22half2_rn(make_float2(a0.z, a0.w));
            eaf[g][kk].h2[2] = __float22half2_rn(make_float2(a1.x, a1.y));
            eaf[g][kk].h2[3] = __float22half2_rn(make_float2(a1.z, a1.w));
        }

    __half2 xs[4][8];
#pragma unroll
    for (int g = 0; g < 4; ++g) {
        int s = ei[ebw + g * 32 + l];
#pragma unroll
        for (int ih = 0; ih < 2; ++ih) {
            float4 a0 = *(const float4*)(x + s * 32 + ih * 16 + half * 8);
            float4 a1 = *(const float4*)(x + s * 32 + ih * 16 + half * 8 + 4);
            xs[g][ih*4+0] = __float22half2_rn(make_float2(a0.x, a0.y));
            xs[g][ih*4+1] = __float22half2_rn(make_float2(a0.z, a0.w));
            xs[g][ih*4+2] = __float22half2_rn(make_float2(a1.x, a1.y));
            xs[g][ih*4+3] = __float22half2_rn(make_float2(a1.z, a1.w));
        }
    }

    f32x16 acc[4];
#pragma unroll
    for (int g = 0; g < 4; ++g)
#pragma unroll
        for (int i = 0; i < 16; ++i) acc[g][i] = 0.f;

    auto phase1 = [&](int r) {
        f16x8 w1f0 = *(const f16x8*)(w1p + ((r * 2 + 0) * 64 + lane) * 8);
        f16x8 w1f1 = *(const f16x8*)(w1p + ((r * 2 + 1) * 64 + lane) * 8);
#pragma unroll
        for (int g = 0; g < 4; ++g) {
            f32x16 h;
#pragma unroll
            for (int i = 0; i < 16; ++i) h[i] = 0.f;
            h = __builtin_amdgcn_mfma_f32_32x32x16_f16(w1f0, eaf[g][0].v, h, 0, 0, 0);
            h = __builtin_amdgcn_mfma_f32_32x32x16_f16(w1f1, eaf[g][1].v, h, 0, 0, 0);
#pragma unroll
            for (int i = 0; i < 16; ++i) {
                int row = (i & 3) + ((i >> 2) << 3) + (half << 2);
                float hv = fmaxf(h[i] + b1[r * 32 + row], 0.f);
                hTq[w][row][l][g] = __half_as_ushort(__float2half(hv));
            }
        }
    };

    auto computeCol = [&](int cs, const f16x8 (&B)[2]) {
        uint2 u = *(const uint2*)&hTq[w][cs][l][0];
        __half2 ha = *reinterpret_cast<const __half2*>(&u.x);
        __half2 hb = *reinterpret_cast<const __half2*>(&u.y);
        __half2 d[4];
        d[0] = __half2half2(__low2half(ha));
        d[1] = __half2half2(__high2half(ha));
        d[2] = __half2half2(__low2half(hb));
        d[3] = __half2half2(__high2half(hb));
#pragma unroll
        for (int ih = 0; ih < 2; ++ih) {
            f16x8 bfr = B[ih];
#pragma unroll
            for (int g = 0; g < 4; ++g) {
                u8h A;
#pragma unroll
                for (int p = 0; p < 4; ++p)
                    A.h2[p] = __hmul2(d[g], xs[g][ih * 4 + p]);
                acc[g] = __builtin_amdgcn_mfma_f32_32x32x16_f16(A.v, bfr, acc[g], 0, 0, 0);
            }
        }
    };

#pragma unroll 1
    for (int r = 0; r < 4; ++r) {
        phase1(r);
#pragma unroll 1
        for (int q = 0; q < 8; ++q) {
            const int j = r * 32 + q * 4;
            computeCol(q * 4 + 0, BA); loadCol(j + 4, BA);
            computeCol(q * 4 + 1, BB); loadCol(j + 5, BB);
            computeCol(q * 4 + 2, BC); loadCol(j + 6, BC);
            computeCol(q * 4 + 3, BD); loadCol(j + 7, BD);
        }
    }

#pragma unroll
    for (int ih = 0; ih < 2; ++ih) {
        f16x8 bfr = *(const f16x8*)(b2p + (ih * 64 + lane) * 8);
#pragma unroll
        for (int g = 0; g < 4; ++g) {
            u8h A;
#pragma unroll
            for (int p = 0; p < 4; ++p) A.h2[p] = xs[g][ih * 4 + p];
            acc[g] = __builtin_amdgcn_mfma_f32_32x32x16_f16(A.v, bfr, acc[g], 0, 0, 0);
        }
    }

    if (live) {
#pragma unroll
        for (int g = 0; g < 4; ++g)
#pragma unroll
            for (int i = 0; i < 16; ++i) {
                int el = (i & 3) + ((i >> 2) << 3) + (half << 2);
                atomicAdd(myout + ei[EE + ebw + g * 32 + el] * 32 + l, acc[g][i]);
            }
    }
}

// ==================== fused cooperative kernel ====================
// grid = 1563 blocks x 128 threads. Phase A: pack + out=x@root+bias.
// grid.sync. Phase B: R13 edge core, atomicAdd into out.
__global__ __launch_bounds__(128, 4) void fused_kernel(
    const float*    __restrict__ x,
    const int*      __restrict__ ei,
    const float*    __restrict__ ea,
    const float*    __restrict__ w1,
    const float*    __restrict__ b1,
    const float*    __restrict__ w2,
    const float*    __restrict__ b2,
    const float*    __restrict__ root,
    const float*    __restrict__ bias,
    _Float16*       __restrict__ w2p,
    _Float16*       __restrict__ w1p,
    _Float16*       __restrict__ b2p,
    float*          __restrict__ out)
{
    __shared__ unsigned short hTq[2][32][32][4];   // 16 KB, wave-private use

    const int tid    = blockIdx.x * 128 + threadIdx.x;
    const int stride = gridDim.x * 128;            // 200064 for grid 1563

    // ---- Phase A: pack w2/w1/b2 into fragment layout (one elem/thread) ----
    for (int t = tid; t < 136192; t += stride) {
        if (t < 131072) {
            int j = t & 7, lane = (t >> 3) & 63, ih = (t >> 9) & 1, c = t >> 10;
            w2p[t] = (_Float16)w2[c * 1024 + (ih * 16 + ((lane >> 5) << 3) + j) * 32 + (lane & 31)];
        } else if (t < 135168) {
            int u = t - 131072;
            int j = u & 7, lane = (u >> 3) & 63, kk = (u >> 9) & 1, r = u >> 10;
            w1p[u] = (_Float16)w1[(kk * 16 + ((lane >> 5) << 3) + j) * 128 + r * 32 + (lane & 31)];
        } else {
            int u = t - 135168;
            int j = u & 7, lane = (u >> 3) & 63, ih = u >> 9;
            b2p[u] = (_Float16)b2[(ih * 16 + ((lane >> 5) << 3) + j) * 32 + (lane & 31)];
        }
    }
    // ---- Phase A: out = x@root + bias (4-5 outputs/thread) ----
    for (int gidx = tid; gidx < NN * 32; gidx += stride) {
        int n = gidx >> 5, o = gidx & 31;
        float a = bias[o];
        const float* xr = x + (n << 5);
#pragma unroll
        for (int i = 0; i < 32; ++i)
            a = fmaf(xr[i], root[(i << 5) + o], a);
        out[gidx] = a;
    }

    cg::this_grid().sync();

    // ---- Phase B: edge core (R13), atomics into out ----
    const int t    = threadIdx.x;
    const int w    = t >> 6;
    const int lane = t & 63;
    const int l    = lane & 31;
    const int half = lane >> 5;

    const int  ebraw = blockIdx.x * 256 + w * 128;
    const bool live  = (ebraw + 128) <= EE;        // wave-uniform; 128 | EE
    const int  ebw   = live ? ebraw : (EE - 128);

    union u8h { f16x8 v; __half2 h2[4]; };

    const f16x8* __restrict__ w2f = (const f16x8*)w2p;

    f16x8 BA[2], BB[2], BC[2], BD[2];              // 4-deep column buffers
    auto loadCol = [&](int j, f16x8 (&B)[2]) {
        const f16x8* p = w2f + (size_t)j * 128 + lane;
        B[0] = p[0];
        B[1] = p[64];
    };
    loadCol(0, BA); loadCol(1, BB); loadCol(2, BC); loadCol(3, BD);

    u8h eaf[4][2];
#pragma unroll
    for (int g = 0; g < 4; ++g)
#pragma unroll
        for (int kk = 0; kk < 2; ++kk) {
            const float* p = ea + (size_t)(ebw + g * 32 + l) * 32 + kk * 16 + half * 8;
            float4 a0 = *(const float4*)p;
            float4 a1 = *(const float4*)(p + 4);
            eaf[g][kk].h2[0] = __float22half2_rn(make_float2(a0.x, a0.y));
            eaf[g][kk].h2[1] = __float22half2_rn(make_float2(a0.z, a0.w));
            eaf[g][kk].h2[2] = __float22half2_rn(make_float2(a1.x, a1.y));
            eaf[g][kk].h2[3] = __float22half2_rn(make_float2(a1.z, a1.w));
        }

    __half2 xs[4][8];
#pragma unroll
    for (int g = 0; g < 4; ++g) {
        int s = ei[ebw + g * 32 + l];
#pragma unroll
        for (int ih = 0; ih < 2; ++ih) {
            float4 a0 = *(const float4*)(x + s * 32 + ih * 16 + half * 8);
            float4 a1 = *(const float4*)(x + s * 32 + ih * 16 + half * 8 + 4);
            xs[g][ih*4+0] = __float22half2_rn(make_float2(a0.x, a0.y));
            xs[g][ih*4+1] = __float22half2_rn(make_float2(a0.z, a0.w));
            xs[g][ih*4+2] = __float22half2_rn(make_float2(a1.x, a1.y));
            xs[g][ih*4+3] = __float22half2_rn(make_float2(a1.z, a1.w));
        }
    }

    f32x16 acc[4];
#pragma unroll
    for (int g = 0; g < 4; ++g)
#pragma unroll
        for (int i = 0; i < 16; ++i) acc[g][i] = 0.f;

    auto phase1 = [&](int r) {
        f16x8 w1f0 = *(const f16x8*)(w1p + ((r * 2 + 0) * 64 + lane) * 8);
        f16x8 w1f1 = *(const f16x8*)(w1p + ((r * 2 + 1) * 64 + lane) * 8);
#pragma unroll
        for (int g = 0; g < 4; ++g) {
            f32x16 h;
#pragma unroll
            for (int i = 0; i < 16; ++i) h[i] = 0.f;
            h = __builtin_amdgcn_mfma_f32_32x32x16_f16(w1f0, eaf[g][0].v, h, 0, 0, 0);
            h = __builtin_amdgcn_mfma_f32_32x32x16_f16(w1f1, eaf[g][1].v, h, 0, 0, 0);
#pragma unroll
            for (int i = 0; i < 16; ++i) {
                int row = (i & 3) + ((i >> 2) << 3) + (half << 2);   // verified C/D map
                float hv = fmaxf(h[i] + b1[r * 32 + row], 0.f);
                hTq[w][row][l][g] = __half_as_ushort(__float2half(hv));
            }
        }
    };

    auto computeCol = [&](int cs, const f16x8 (&B)[2]) {
        uint2 u = *(const uint2*)&hTq[w][cs][l][0];
        __half2 ha = *reinterpret_cast<const __half2*>(&u.x);
        __half2 hb = *reinterpret_cast<const __half2*>(&u.y);
        __half2 d[4];
        d[0] = __half2half2(__low2half(ha));
        d[1] = __half2half2(__high2half(ha));
        d[2] = __half2half2(__low2half(hb));
        d[3] = __half2half2(__high2half(hb));
#pragma unroll
        for (int ih = 0; ih < 2; ++ih) {
            f16x8 bfr = B[ih];
#pragma unroll
            for (int g = 0; g < 4; ++g) {
                u8h A;
#pragma unroll
                for (int p = 0; p < 4; ++p)
                    A.h2[p] = __hmul2(d[g], xs[g][ih * 4 + p]);   // v_pk_mul_f16
                acc[g] = __builtin_amdgcn_mfma_f32_32x32x16_f16(A.v, bfr, acc[g], 0, 0, 0);
            }
        }
    };

#pragma unroll 1
    for (int r = 0; r < 4; ++r) {
        phase1(r);                     // wave-private hTq: no barrier needed
#pragma unroll 1
        for (int q = 0; q < 8; ++q) {
            const int j = r * 32 + q * 4;
            computeCol(q * 4 + 0, BA); loadCol(j + 4, BA);
            computeCol(q * 4 + 1, BB); loadCol(j + 5, BB);
            computeCol(q * 4 + 2, BC); loadCol(j + 6, BC);
            computeCol(q * 4 + 3, BD); loadCol(j + 7, BD);
        }
    }

#pragma unroll
    for (int ih = 0; ih < 2; ++ih) {
        f16x8 bfr = *(const f16x8*)(b2p + (ih * 64 + lane) * 8);
#pragma unroll
        for (int g = 0; g < 4; ++g) {
            u8h A;
#pragma unroll
            for (int p = 0; p < 4; ++p) A.h2[p] = xs[g][ih * 4 + p];
            acc[g] = __builtin_amdgcn_mfma_f32_32x32x16_f16(A.v, bfr, acc[g], 0, 0, 0);
        }
    }

    if (live) {
#pragma unroll
        for (int g = 0; g < 4; ++g)
#pragma unroll
            for (int i = 0; i < 16; ++i) {
                int el = (i & 3) + ((i >> 2) << 3) + (half << 2);
                atomicAdd(out + (size_t)ei[EE + ebw + g * 32 + el] * 32 + l, acc[g][i]);
            }
    }
}

extern "C" void kernel_launch(void* const* d_in, const int* in_sizes, int n_in,
                              void* d_out, int out_size, void* d_ws, size_t ws_size,
                              hipStream_t stream) {
    const float* x    = (const float*)d_in[0];
    const int*   ei   = (const int*)  d_in[1];
    const float* ea   = (const float*)d_in[2];
    const float* w1   = (const float*)d_in[3];
    const float* b1   = (const float*)d_in[4];
    const float* w2   = (const float*)d_in[5];
    const float* b2   = (const float*)d_in[6];
    const float* root = (const float*)d_in[7];
    const float* bias = (const float*)d_in[8];
    float* out = (float*)d_out;

    _Float16* w2p = (_Float16*)d_ws;                      // 262144 B
    _Float16* w1p = (_Float16*)((char*)d_ws + 262144);    //   8192 B
    _Float16* b2p = (_Float16*)((char*)d_ws + 270336);    //   2048 B

    // ---- try single cooperative launch ----
    const int GRID = (EE + 255) / 256;                    // 1563
    int nb = 0;
    hipError_t qe = hipOccupancyMaxActiveBlocksPerMultiprocessor(&nb, fused_kernel, 128, 0);
    bool launched = false;
    if (qe == hipSuccess && nb * 256 >= GRID) {
        void* args[] = {
            (void*)&x, (void*)&ei, (void*)&ea, (void*)&w1, (void*)&b1,
            (void*)&w2, (void*)&b2, (void*)&root, (void*)&bias,
            (void*)&w2p, (void*)&w1p, (void*)&b2p, (void*)&out
        };
        hipError_t le = hipLaunchCooperativeKernel(
            (const void*)fused_kernel, dim3(GRID), dim3(128), args, 0, stream);
        launched = (le == hipSuccess);
    }
    if (launched) return;

    // ---- fallback: R13 3-launch replica-atomic path ----
    const size_t partOff = 272384;
    const size_t one = 800000ull * sizeof(float);         // 3.2 MB per replica
    size_t avail = (ws_size > partOff) ? ws_size - partOff : 0;
    int nc = 0;
    for (int c = 8; c >= 1; c >>= 1)
        if ((size_t)c * one <= avail) { nc = c; break; }

    float* part = (float*)((char*)d_ws + partOff);
    if (nc > 0) {
        int nzero4 = nc * 200000;
        int zb = (nzero4 + 255) / 256;
        prep_kernel<<<532 + zb, 256, 0, stream>>>(w1, w2, b2, w2p, w1p, b2p,
                                                  (float4*)part, nzero4);
        edge_kernel<<<GRID, 128, 0, stream>>>(x, ei, ea, b1, w2p, w1p, b2p,
                                              part, nc - 1);
        final_kernel<<<(NN * 32) / 256, 256, 0, stream>>>(x, root, bias, part, nc, out);
    } else {
        prep_kernel<<<532, 256, 0, stream>>>(w1, w2, b2, w2p, w1p, b2p, (float4*)part, 0);
        final_kernel<<<(NN * 32) / 256, 256, 0, stream>>>(x, root, bias, part, 0, out);
        edge_kernel<<<GRID, 128, 0, stream>>>(x, ei, ea, b1, w2p, w1p, b2p,
                                              out, 0);
    }
}

// Round 6
// 234.602 us; speedup vs baseline: 1.3974x; 1.0033x over previous
//
#include <hip/hip_runtime.h>
#include <hip/hip_fp16.h>
#include <hip/hip_cooperative_groups.h>

// NNConv on MI355X. msg[E x 32] = Z[E x 4096] @ w2r[4096 x 32],
// Z[e, c*32+i] = h[e,c]*xs[e,i] built on the fly in fp16 A-fragments via
// v_pk_mul_f16.
// Round 16: R15's single cooperative launch with the REGISTER CAP FIXED.
// Empirical __launch_bounds__ law on this toolchain (R12/R13/R15: caps
// 84/128/64 at args 3/2/4, 2-wave blocks): VGPR cap = 512/(arg * waves
// per block) -- the 2nd arg acts as min WORKGROUPS per EU. R15's (128,4)
// imposed a 64-reg cap -> 465 MB of spill (WRITE 520 MB) -> fused kernel
// ran ~210 us. (128,2) = 128-reg cap, the exact bound under which this
// core compiled spill-free in R13, and 8 blocks/CU co-residency
// (2048 >= 1563). Everything else unchanged from R15.

#define NN 25000
#define EE 400000

namespace cg = cooperative_groups;

typedef _Float16 f16x8 __attribute__((ext_vector_type(8)));
typedef float    f32x16 __attribute__((ext_vector_type(16)));

// ==================== fallback kernels (R13 path) ====================

__global__ __launch_bounds__(256) void prep_kernel(
    const float* __restrict__ w1, const float* __restrict__ w2,
    const float* __restrict__ b2,
    _Float16* __restrict__ w2p, _Float16* __restrict__ w1p, _Float16* __restrict__ b2p,
    float4* __restrict__ zero4, int nzero4)
{
    int b = blockIdx.x;
    if (b < 532) {
        int t = b * 256 + threadIdx.x;
        if (t < 131072) {
            int j = t & 7, lane = (t >> 3) & 63, ih = (t >> 9) & 1, c = t >> 10;
            w2p[t] = (_Float16)w2[c * 1024 + (ih * 16 + ((lane >> 5) << 3) + j) * 32 + (lane & 31)];
        } else if (t < 135168) {
            int u = t - 131072;
            int j = u & 7, lane = (u >> 3) & 63, kk = (u >> 9) & 1, r = u >> 10;
            w1p[u] = (_Float16)w1[(kk * 16 + ((lane >> 5) << 3) + j) * 128 + r * 32 + (lane & 31)];
        } else {
            int u = t - 135168;
            int j = u & 7, lane = (u >> 3) & 63, ih = u >> 9;
            b2p[u] = (_Float16)b2[(ih * 16 + ((lane >> 5) << 3) + j) * 32 + (lane & 31)];
        }
    } else {
        int z = (b - 532) * 256 + threadIdx.x;
        if (z < nzero4) zero4[z] = make_float4(0.f, 0.f, 0.f, 0.f);
    }
}

__global__ __launch_bounds__(256) void final_kernel(
    const float* __restrict__ x, const float* __restrict__ root,
    const float* __restrict__ bias, const float* __restrict__ part,
    int ncopies, float* __restrict__ out)
{
    int gid = blockIdx.x * 256 + threadIdx.x;
    int n = gid >> 5, o = gid & 31;
    float acc = bias[o];
    const float* xr = x + (n << 5);
#pragma unroll
    for (int i = 0; i < 32; ++i)
        acc = fmaf(xr[i], root[(i << 5) + o], acc);
    for (int c = 0; c < ncopies; ++c) acc += part[(size_t)c * 800000 + gid];
    out[gid] = acc;
}

__global__ __launch_bounds__(128, 2) void edge_kernel(
    const float*    __restrict__ x,
    const int*      __restrict__ ei,
    const float*    __restrict__ ea,
    const float*    __restrict__ b1,
    const _Float16* __restrict__ w2p,
    const _Float16* __restrict__ w1p,
    const _Float16* __restrict__ b2p,
    float* __restrict__ outp, int copyMask)
{
    __shared__ unsigned short hTq[2][32][32][4];

    const int t    = threadIdx.x;
    const int w    = t >> 6;
    const int lane = t & 63;
    const int l    = lane & 31;
    const int half = lane >> 5;

    const int  ebraw = blockIdx.x * 256 + w * 128;
    const bool live  = (ebraw + 128) <= EE;
    const int  ebw   = live ? ebraw : (EE - 128);

    float* __restrict__ myout = outp + (size_t)(blockIdx.x & copyMask) * 800000;

    union u8h { f16x8 v; __half2 h2[4]; };

    const f16x8* __restrict__ w2f = (const f16x8*)w2p;

    f16x8 BA[2], BB[2], BC[2], BD[2];
    auto loadCol = [&](int j, f16x8 (&B)[2]) {
        const f16x8* p = w2f + (size_t)j * 128 + lane;
        B[0] = p[0];
        B[1] = p[64];
    };
    loadCol(0, BA); loadCol(1, BB); loadCol(2, BC); loadCol(3, BD);

    u8h eaf[4][2];
#pragma unroll
    for (int g = 0; g < 4; ++g)
#pragma unroll
        for (int kk = 0; kk < 2; ++kk) {
            const float* p = ea + (size_t)(ebw + g * 32 + l) * 32 + kk * 16 + half * 8;
            float4 a0 = *(const float4*)p;
            float4 a1 = *(const float4*)(p + 4);
            eaf[g][kk].h2[0] = __float22half2_rn(make_float2(a0.x, a0.y));
            eaf[g][kk].h2[1] = __float22half2_rn(make_float2(a0.z, a0.w));
            eaf[g][kk].h2[2] = __float22half2_rn(make_float2(a1.x, a1.y));
            eaf[g][kk].h2[3] = __float22half2_rn(make_float2(a1.z, a1.w));
        }

    __half2 xs[4][8];
#pragma unroll
    for (int g = 0; g < 4; ++g) {
        int s = ei[ebw + g * 32 + l];
#pragma unroll
        for (int ih = 0; ih < 2; ++ih) {
            float4 a0 = *(const float4*)(x + s * 32 + ih * 16 + half * 8);
            float4 a1 = *(const float4*)(x + s * 32 + ih * 16 + half * 8 + 4);
            xs[g][ih*4+0] = __float22half2_rn(make_float2(a0.x, a0.y));
            xs[g][ih*4+1] = __float22half2_rn(make_float2(a0.z, a0.w));
            xs[g][ih*4+2] = __float22half2_rn(make_float2(a1.x, a1.y));
            xs[g][ih*4+3] = __float22half2_rn(make_float2(a1.z, a1.w));
        }
    }

    f32x16 acc[4];
#pragma unroll
    for (int g = 0; g < 4; ++g)
#pragma unroll
        for (int i = 0; i < 16; ++i) acc[g][i] = 0.f;

    auto phase1 = [&](int r) {
        f16x8 w1f0 = *(const f16x8*)(w1p + ((r * 2 + 0) * 64 + lane) * 8);
        f16x8 w1f1 = *(const f16x8*)(w1p + ((r * 2 + 1) * 64 + lane) * 8);
#pragma unroll
        for (int g = 0; g < 4; ++g) {
            f32x16 h;
#pragma unroll
            for (int i = 0; i < 16; ++i) h[i] = 0.f;
            h = __builtin_amdgcn_mfma_f32_32x32x16_f16(w1f0, eaf[g][0].v, h, 0, 0, 0);
            h = __builtin_amdgcn_mfma_f32_32x32x16_f16(w1f1, eaf[g][1].v, h, 0, 0, 0);
#pragma unroll
            for (int i = 0; i < 16; ++i) {
                int row = (i & 3) + ((i >> 2) << 3) + (half << 2);
                float hv = fmaxf(h[i] + b1[r * 32 + row], 0.f);
                hTq[w][row][l][g] = __half_as_ushort(__float2half(hv));
            }
        }
    };

    auto computeCol = [&](int cs, const f16x8 (&B)[2]) {
        uint2 u = *(const uint2*)&hTq[w][cs][l][0];
        __half2 ha = *reinterpret_cast<const __half2*>(&u.x);
        __half2 hb = *reinterpret_cast<const __half2*>(&u.y);
        __half2 d[4];
        d[0] = __half2half2(__low2half(ha));
        d[1] = __half2half2(__high2half(ha));
        d[2] = __half2half2(__low2half(hb));
        d[3] = __half2half2(__high2half(hb));
#pragma unroll
        for (int ih = 0; ih < 2; ++ih) {
            f16x8 bfr = B[ih];
#pragma unroll
            for (int g = 0; g < 4; ++g) {
                u8h A;
#pragma unroll
                for (int p = 0; p < 4; ++p)
                    A.h2[p] = __hmul2(d[g], xs[g][ih * 4 + p]);
                acc[g] = __builtin_amdgcn_mfma_f32_32x32x16_f16(A.v, bfr, acc[g], 0, 0, 0);
            }
        }
    };

#pragma unroll 1
    for (int r = 0; r < 4; ++r) {
        phase1(r);
#pragma unroll 1
        for (int q = 0; q < 8; ++q) {
            const int j = r * 32 + q * 4;
            computeCol(q * 4 + 0, BA); loadCol(j + 4, BA);
            computeCol(q * 4 + 1, BB); loadCol(j + 5, BB);
            computeCol(q * 4 + 2, BC); loadCol(j + 6, BC);
            computeCol(q * 4 + 3, BD); loadCol(j + 7, BD);
        }
    }

#pragma unroll
    for (int ih = 0; ih < 2; ++ih) {
        f16x8 bfr = *(const f16x8*)(b2p + (ih * 64 + lane) * 8);
#pragma unroll
        for (int g = 0; g < 4; ++g) {
            u8h A;
#pragma unroll
            for (int p = 0; p < 4; ++p) A.h2[p] = xs[g][ih * 4 + p];
            acc[g] = __builtin_amdgcn_mfma_f32_32x32x16_f16(A.v, bfr, acc[g], 0, 0, 0);
        }
    }

    if (live) {
#pragma unroll
        for (int g = 0; g < 4; ++g)
#pragma unroll
            for (int i = 0; i < 16; ++i) {
                int el = (i & 3) + ((i >> 2) << 3) + (half << 2);
                atomicAdd(myout + ei[EE + ebw + g * 32 + el] * 32 + l, acc[g][i]);
            }
    }
}

// ==================== fused cooperative kernel ====================
// grid = 1563 blocks x 128 threads. Phase A: pack + out=x@root+bias.
// grid.sync. Phase B: R13 edge core, atomicAdd into out.
// (128,2): empirically = 128-VGPR cap (no spill for this core, per R13)
// and 8 blocks/CU co-residency (2048 >= 1563).
__global__ __launch_bounds__(128, 2) void fused_kernel(
    const float*    __restrict__ x,
    const int*      __restrict__ ei,
    const float*    __restrict__ ea,
    const float*    __restrict__ w1,
    const float*    __restrict__ b1,
    const float*    __restrict__ w2,
    const float*    __restrict__ b2,
    const float*    __restrict__ root,
    const float*    __restrict__ bias,
    _Float16*       __restrict__ w2p,
    _Float16*       __restrict__ w1p,
    _Float16*       __restrict__ b2p,
    float*          __restrict__ out)
{
    __shared__ unsigned short hTq[2][32][32][4];   // 16 KB, wave-private use

    const int tid    = blockIdx.x * 128 + threadIdx.x;
    const int stride = gridDim.x * 128;            // 200064 for grid 1563

    // ---- Phase A: pack w2/w1/b2 into fragment layout (one elem/thread) ----
    for (int t = tid; t < 136192; t += stride) {
        if (t < 131072) {
            int j = t & 7, lane = (t >> 3) & 63, ih = (t >> 9) & 1, c = t >> 10;
            w2p[t] = (_Float16)w2[c * 1024 + (ih * 16 + ((lane >> 5) << 3) + j) * 32 + (lane & 31)];
        } else if (t < 135168) {
            int u = t - 131072;
            int j = u & 7, lane = (u >> 3) & 63, kk = (u >> 9) & 1, r = u >> 10;
            w1p[u] = (_Float16)w1[(kk * 16 + ((lane >> 5) << 3) + j) * 128 + r * 32 + (lane & 31)];
        } else {
            int u = t - 135168;
            int j = u & 7, lane = (u >> 3) & 63, ih = u >> 9;
            b2p[u] = (_Float16)b2[(ih * 16 + ((lane >> 5) << 3) + j) * 32 + (lane & 31)];
        }
    }
    // ---- Phase A: out = x@root + bias (4-5 outputs/thread) ----
    for (int gidx = tid; gidx < NN * 32; gidx += stride) {
        int n = gidx >> 5, o = gidx & 31;
        float a = bias[o];
        const float* xr = x + (n << 5);
#pragma unroll
        for (int i = 0; i < 32; ++i)
            a = fmaf(xr[i], root[(i << 5) + o], a);
        out[gidx] = a;
    }

    cg::this_grid().sync();

    // ---- Phase B: edge core (R13), atomics into out ----
    const int t    = threadIdx.x;
    const int w    = t >> 6;
    const int lane = t & 63;
    const int l    = lane & 31;
    const int half = lane >> 5;

    const int  ebraw = blockIdx.x * 256 + w * 128;
    const bool live  = (ebraw + 128) <= EE;        // wave-uniform; 128 | EE
    const int  ebw   = live ? ebraw : (EE - 128);

    union u8h { f16x8 v; __half2 h2[4]; };

    const f16x8* __restrict__ w2f = (const f16x8*)w2p;

    f16x8 BA[2], BB[2], BC[2], BD[2];              // 4-deep column buffers
    auto loadCol = [&](int j, f16x8 (&B)[2]) {
        const f16x8* p = w2f + (size_t)j * 128 + lane;
        B[0] = p[0];
        B[1] = p[64];
    };
    loadCol(0, BA); loadCol(1, BB); loadCol(2, BC); loadCol(3, BD);

    u8h eaf[4][2];
#pragma unroll
    for (int g = 0; g < 4; ++g)
#pragma unroll
        for (int kk = 0; kk < 2; ++kk) {
            const float* p = ea + (size_t)(ebw + g * 32 + l) * 32 + kk * 16 + half * 8;
            float4 a0 = *(const float4*)p;
            float4 a1 = *(const float4*)(p + 4);
            eaf[g][kk].h2[0] = __float22half2_rn(make_float2(a0.x, a0.y));
            eaf[g][kk].h2[1] = __float22half2_rn(make_float2(a0.z, a0.w));
            eaf[g][kk].h2[2] = __float22half2_rn(make_float2(a1.x, a1.y));
            eaf[g][kk].h2[3] = __float22half2_rn(make_float2(a1.z, a1.w));
        }

    __half2 xs[4][8];
#pragma unroll
    for (int g = 0; g < 4; ++g) {
        int s = ei[ebw + g * 32 + l];
#pragma unroll
        for (int ih = 0; ih < 2; ++ih) {
            float4 a0 = *(const float4*)(x + s * 32 + ih * 16 + half * 8);
            float4 a1 = *(const float4*)(x + s * 32 + ih * 16 + half * 8 + 4);
            xs[g][ih*4+0] = __float22half2_rn(make_float2(a0.x, a0.y));
            xs[g][ih*4+1] = __float22half2_rn(make_float2(a0.z, a0.w));
            xs[g][ih*4+2] = __float22half2_rn(make_float2(a1.x, a1.y));
            xs[g][ih*4+3] = __float22half2_rn(make_float2(a1.z, a1.w));
        }
    }

    f32x16 acc[4];
#pragma unroll
    for (int g = 0; g < 4; ++g)
#pragma unroll
        for (int i = 0; i < 16; ++i) acc[g][i] = 0.f;

    auto phase1 = [&](int r) {
        f16x8 w1f0 = *(const f16x8*)(w1p + ((r * 2 + 0) * 64 + lane) * 8);
        f16x8 w1f1 = *(const f16x8*)(w1p + ((r * 2 + 1) * 64 + lane) * 8);
#pragma unroll
        for (int g = 0; g < 4; ++g) {
            f32x16 h;
#pragma unroll
            for (int i = 0; i < 16; ++i) h[i] = 0.f;
            h = __builtin_amdgcn_mfma_f32_32x32x16_f16(w1f0, eaf[g][0].v, h, 0, 0, 0);
            h = __builtin_amdgcn_mfma_f32_32x32x16_f16(w1f1, eaf[g][1].v, h, 0, 0, 0);
#pragma unroll
            for (int i = 0; i < 16; ++i) {
                int row = (i & 3) + ((i >> 2) << 3) + (half << 2);   // verified C/D map
                float hv = fmaxf(h[i] + b1[r * 32 + row], 0.f);
                hTq[w][row][l][g] = __half_as_ushort(__float2half(hv));
            }
        }
    };

    auto computeCol = [&](int cs, const f16x8 (&B)[2]) {
        uint2 u = *(const uint2*)&hTq[w][cs][l][0];
        __half2 ha = *reinterpret_cast<const __half2*>(&u.x);
        __half2 hb = *reinterpret_cast<const __half2*>(&u.y);
        __half2 d[4];
        d[0] = __half2half2(__low2half(ha));
        d[1] = __half2half2(__high2half(ha));
        d[2] = __half2half2(__low2half(hb));
        d[3] = __half2half2(__high2half(hb));
#pragma unroll
        for (int ih = 0; ih < 2; ++ih) {
            f16x8 bfr = B[ih];
#pragma unroll
            for (int g = 0; g < 4; ++g) {
                u8h A;
#pragma unroll
                for (int p = 0; p < 4; ++p)
                    A.h2[p] = __hmul2(d[g], xs[g][ih * 4 + p]);   // v_pk_mul_f16
                acc[g] = __builtin_amdgcn_mfma_f32_32x32x16_f16(A.v, bfr, acc[g], 0, 0, 0);
            }
        }
    };

#pragma unroll 1
    for (int r = 0; r < 4; ++r) {
        phase1(r);                     // wave-private hTq: no barrier needed
#pragma unroll 1
        for (int q = 0; q < 8; ++q) {
            const int j = r * 32 + q * 4;
            computeCol(q * 4 + 0, BA); loadCol(j + 4, BA);
            computeCol(q * 4 + 1, BB); loadCol(j + 5, BB);
            computeCol(q * 4 + 2, BC); loadCol(j + 6, BC);
            computeCol(q * 4 + 3, BD); loadCol(j + 7, BD);
        }
    }

#pragma unroll
    for (int ih = 0; ih < 2; ++ih) {
        f16x8 bfr = *(const f16x8*)(b2p + (ih * 64 + lane) * 8);
#pragma unroll
        for (int g = 0; g < 4; ++g) {
            u8h A;
#pragma unroll
            for (int p = 0; p < 4; ++p) A.h2[p] = xs[g][ih * 4 + p];
            acc[g] = __builtin_amdgcn_mfma_f32_32x32x16_f16(A.v, bfr, acc[g], 0, 0, 0);
        }
    }

    if (live) {
#pragma unroll
        for (int g = 0; g < 4; ++g)
#pragma unroll
            for (int i = 0; i < 16; ++i) {
                int el = (i & 3) + ((i >> 2) << 3) + (half << 2);
                atomicAdd(out + (size_t)ei[EE + ebw + g * 32 + el] * 32 + l, acc[g][i]);
            }
    }
}

extern "C" void kernel_launch(void* const* d_in, const int* in_sizes, int n_in,
                              void* d_out, int out_size, void* d_ws, size_t ws_size,
                              hipStream_t stream) {
    const float* x    = (const float*)d_in[0];
    const int*   ei   = (const int*)  d_in[1];
    const float* ea   = (const float*)d_in[2];
    const float* w1   = (const float*)d_in[3];
    const float* b1   = (const float*)d_in[4];
    const float* w2   = (const float*)d_in[5];
    const float* b2   = (const float*)d_in[6];
    const float* root = (const float*)d_in[7];
    const float* bias = (const float*)d_in[8];
    float* out = (float*)d_out;

    _Float16* w2p = (_Float16*)d_ws;                      // 262144 B
    _Float16* w1p = (_Float16*)((char*)d_ws + 262144);    //   8192 B
    _Float16* b2p = (_Float16*)((char*)d_ws + 270336);    //   2048 B

    // ---- try single cooperative launch ----
    const int GRID = (EE + 255) / 256;                    // 1563
    int nb = 0;
    hipError_t qe = hipOccupancyMaxActiveBlocksPerMultiprocessor(&nb, fused_kernel, 128, 0);
    bool launched = false;
    if (qe == hipSuccess && nb * 256 >= GRID) {
        void* args[] = {
            (void*)&x, (void*)&ei, (void*)&ea, (void*)&w1, (void*)&b1,
            (void*)&w2, (void*)&b2, (void*)&root, (void*)&bias,
            (void*)&w2p, (void*)&w1p, (void*)&b2p, (void*)&out
        };
        hipError_t le = hipLaunchCooperativeKernel(
            (const void*)fused_kernel, dim3(GRID), dim3(128), args, 0, stream);
        launched = (le == hipSuccess);
    }
    if (launched) return;

    // ---- fallback: R13 3-launch replica-atomic path ----
    const size_t partOff = 272384;
    const size_t one = 800000ull * sizeof(float);         // 3.2 MB per replica
    size_t avail = (ws_size > partOff) ? ws_size - partOff : 0;
    int nc = 0;
    for (int c = 8; c >= 1; c >>= 1)
        if ((size_t)c * one <= avail) { nc = c; break; }

    float* part = (float*)((char*)d_ws + partOff);
    if (nc > 0) {
        int nzero4 = nc * 200000;
        int zb = (nzero4 + 255) / 256;
        prep_kernel<<<532 + zb, 256, 0, stream>>>(w1, w2, b2, w2p, w1p, b2p,
                                                  (float4*)part, nzero4);
        edge_kernel<<<GRID, 128, 0, stream>>>(x, ei, ea, b1, w2p, w1p, b2p,
                                              part, nc - 1);
        final_kernel<<<(NN * 32) / 256, 256, 0, stream>>>(x, root, bias, part, nc, out);
    } else {
        prep_kernel<<<532, 256, 0, stream>>>(w1, w2, b2, w2p, w1p, b2p, (float4*)part, 0);
        final_kernel<<<(NN * 32) / 256, 256, 0, stream>>>(x, root, bias, part, 0, out);
        edge_kernel<<<GRID, 128, 0, stream>>>(x, ei, ea, b1, w2p, w1p, b2p,
                                              out, 0);
    }
}

// Round 7
// 225.516 us; speedup vs baseline: 1.4537x; 1.0403x over previous
//
#include <hip/hip_runtime.h>
#include <hip/hip_fp16.h>

// NNConv on MI355X. msg[E x 32] = Z[E x 4096] @ w2r[4096 x 32],
// Z[e, c*32+i] = h[e,c]*xs[e,i] built on the fly in fp16 A-fragments via
// v_pk_mul_f16.
// Round 17: TWO launches. R15/R16 proved cooperative launch is not
// graph-capturable (timed runs always fell back to the 3-launch path;
// bench == R13 to within noise). Launch overhead ~23-27 us/launch is
// robust across R13/R14/R16 fits. prep and final are mutually
// independent, so: launch 1 = prep_final (pack w2/w1/b2 + out =
// x@root + bias); launch 2 = edge core (R13, unchanged) atomicAdd
// straight into out. Stream ordering replaces grid.sync. No replicas,
// no zeroing. Edge core untouched: 4 groups/wave, 4-deep B-column
// register double-buffer, barrier-free, (128,2) = 128-VGPR cap.

#define NN 25000
#define EE 400000

typedef _Float16 f16x8 __attribute__((ext_vector_type(8)));
typedef float    f32x16 __attribute__((ext_vector_type(16)));

// ---------------- launch 1: pack w1/w2/b2 + out = x@root + bias ----------------
// grid 3125 x 256 = 800000 threads, one out element each; first 136192
// threads also pack one fp16 weight element.
__global__ __launch_bounds__(256) void prep_final_kernel(
    const float* __restrict__ x, const float* __restrict__ root,
    const float* __restrict__ bias,
    const float* __restrict__ w1, const float* __restrict__ w2,
    const float* __restrict__ b2,
    _Float16* __restrict__ w2p, _Float16* __restrict__ w1p, _Float16* __restrict__ b2p,
    float* __restrict__ out)
{
    const int t = blockIdx.x * 256 + threadIdx.x;

    // ---- pack (first 136192 threads) ----
    if (t < 131072) {
        int j = t & 7, lane = (t >> 3) & 63, ih = (t >> 9) & 1, c = t >> 10;
        w2p[t] = (_Float16)w2[c * 1024 + (ih * 16 + ((lane >> 5) << 3) + j) * 32 + (lane & 31)];
    } else if (t < 135168) {
        int u = t - 131072;
        int j = u & 7, lane = (u >> 3) & 63, kk = (u >> 9) & 1, r = u >> 10;
        w1p[u] = (_Float16)w1[(kk * 16 + ((lane >> 5) << 3) + j) * 128 + r * 32 + (lane & 31)];
    } else if (t < 136192) {
        int u = t - 135168;
        int j = u & 7, lane = (u >> 3) & 63, ih = u >> 9;
        b2p[u] = (_Float16)b2[(ih * 16 + ((lane >> 5) << 3) + j) * 32 + (lane & 31)];
    }

    // ---- out = x@root + bias (every thread, exactly NN*32 threads) ----
    int n = t >> 5, o = t & 31;
    float acc = bias[o];
    const float* xr = x + (n << 5);
#pragma unroll
    for (int i = 0; i < 32; ++i)
        acc = fmaf(xr[i], root[(i << 5) + o], acc);
    out[t] = acc;
}

// ---------------- launch 2: fused MFMA edge kernel (barrier-free, 4 groups/wave) ----------------
// 128 thr = 2 waves x 128 edges (4 groups of 32) = 256 edges/block, 1563 blocks.
__global__ __launch_bounds__(128, 2) void edge_kernel(
    const float*    __restrict__ x,
    const int*      __restrict__ ei,
    const float*    __restrict__ ea,
    const float*    __restrict__ b1,
    const _Float16* __restrict__ w2p,
    const _Float16* __restrict__ w1p,
    const _Float16* __restrict__ b2p,
    float* __restrict__ out)
{
    __shared__ unsigned short hTq[2][32][32][4];   // 16 KB: [wave][c_in_slice][l][g]

    const int t    = threadIdx.x;
    const int w    = t >> 6;
    const int lane = t & 63;
    const int l    = lane & 31;
    const int half = lane >> 5;

    const int  ebraw = blockIdx.x * 256 + w * 128;
    const bool live  = (ebraw + 128) <= EE;        // wave-uniform; 128 | EE
    const int  ebw   = live ? ebraw : (EE - 128);

    union u8h { f16x8 v; __half2 h2[4]; };

    // ---- w2 B-columns read DIRECTLY from global (L2-resident, 256 KB) ----
    const f16x8* __restrict__ w2f = (const f16x8*)w2p;

    f16x8 BA[2], BB[2], BC[2], BD[2];              // 4-deep column buffers
    auto loadCol = [&](int j, f16x8 (&B)[2]) {
        const f16x8* p = w2f + (size_t)j * 128 + lane;
        B[0] = p[0];
        B[1] = p[64];
    };
    loadCol(0, BA); loadCol(1, BB); loadCol(2, BC); loadCol(3, BD);

    // ---- persistent edge-attr fragments (fp16), 4 groups; read ONCE (32 VGPR) ----
    u8h eaf[4][2];
#pragma unroll
    for (int g = 0; g < 4; ++g)
#pragma unroll
        for (int kk = 0; kk < 2; ++kk) {
            const float* p = ea + (size_t)(ebw + g * 32 + l) * 32 + kk * 16 + half * 8;
            float4 a0 = *(const float4*)p;
            float4 a1 = *(const float4*)(p + 4);
            eaf[g][kk].h2[0] = __float22half2_rn(make_float2(a0.x, a0.y));
            eaf[g][kk].h2[1] = __float22half2_rn(make_float2(a0.z, a0.w));
            eaf[g][kk].h2[2] = __float22half2_rn(make_float2(a1.x, a1.y));
            eaf[g][kk].h2[3] = __float22half2_rn(make_float2(a1.z, a1.w));
        }

    // ---- gather xs rows (fp16 pairs) for 4 groups: 32 VGPRs ----
    __half2 xs[4][8];
#pragma unroll
    for (int g = 0; g < 4; ++g) {
        int s = ei[ebw + g * 32 + l];
#pragma unroll
        for (int ih = 0; ih < 2; ++ih) {
            float4 a0 = *(const float4*)(x + s * 32 + ih * 16 + half * 8);
            float4 a1 = *(const float4*)(x + s * 32 + ih * 16 + half * 8 + 4);
            xs[g][ih*4+0] = __float22half2_rn(make_float2(a0.x, a0.y));
            xs[g][ih*4+1] = __float22half2_rn(make_float2(a0.z, a0.w));
            xs[g][ih*4+2] = __float22half2_rn(make_float2(a1.x, a1.y));
            xs[g][ih*4+3] = __float22half2_rn(make_float2(a1.z, a1.w));
        }
    }

    f32x16 acc[4];
#pragma unroll
    for (int g = 0; g < 4; ++g)
#pragma unroll
        for (int i = 0; i < 16; ++i) acc[g][i] = 0.f;

    // ---- phase-1 slice for r: all 32 rows of hT for 4 groups into LDS ----
    auto phase1 = [&](int r) {
        f16x8 w1f0 = *(const f16x8*)(w1p + ((r * 2 + 0) * 64 + lane) * 8);
        f16x8 w1f1 = *(const f16x8*)(w1p + ((r * 2 + 1) * 64 + lane) * 8);
#pragma unroll
        for (int g = 0; g < 4; ++g) {
            f32x16 h;
#pragma unroll
            for (int i = 0; i < 16; ++i) h[i] = 0.f;
            h = __builtin_amdgcn_mfma_f32_32x32x16_f16(w1f0, eaf[g][0].v, h, 0, 0, 0);
            h = __builtin_amdgcn_mfma_f32_32x32x16_f16(w1f1, eaf[g][1].v, h, 0, 0, 0);
#pragma unroll
            for (int i = 0; i < 16; ++i) {
                int row = (i & 3) + ((i >> 2) << 3) + (half << 2);   // verified C/D map
                float hv = fmaxf(h[i] + b1[r * 32 + row], 0.f);
                hTq[w][row][l][g] = __half_as_ushort(__float2half(hv));
            }
        }
    };

    // compute one c-column (8 MFMAs: 2 ih x 4 g) from register fragments
    auto computeCol = [&](int cs, const f16x8 (&B)[2]) {
        uint2 u = *(const uint2*)&hTq[w][cs][l][0];
        __half2 ha = *reinterpret_cast<const __half2*>(&u.x);
        __half2 hb = *reinterpret_cast<const __half2*>(&u.y);
        __half2 d[4];
        d[0] = __half2half2(__low2half(ha));
        d[1] = __half2half2(__high2half(ha));
        d[2] = __half2half2(__low2half(hb));
        d[3] = __half2half2(__high2half(hb));
#pragma unroll
        for (int ih = 0; ih < 2; ++ih) {
            f16x8 bfr = B[ih];
#pragma unroll
            for (int g = 0; g < 4; ++g) {
                u8h A;
#pragma unroll
                for (int p = 0; p < 4; ++p)
                    A.h2[p] = __hmul2(d[g], xs[g][ih * 4 + p]);   // v_pk_mul_f16
                acc[g] = __builtin_amdgcn_mfma_f32_32x32x16_f16(A.v, bfr, acc[g], 0, 0, 0);
            }
        }
    };

    // ---- pipeline: no barriers; 3-col prefetch distance via 4 buffers.
    // Max overread: col 131 -> lands in w1p/b2p workspace region (valid
    // memory, values unused). ----
#pragma unroll 1
    for (int r = 0; r < 4; ++r) {
        phase1(r);                     // wave-private hTq: no barrier needed
#pragma unroll 1
        for (int q = 0; q < 8; ++q) {
            const int j = r * 32 + q * 4;
            computeCol(q * 4 + 0, BA); loadCol(j + 4, BA);
            computeCol(q * 4 + 1, BB); loadCol(j + 5, BB);
            computeCol(q * 4 + 2, BC); loadCol(j + 6, BC);
            computeCol(q * 4 + 3, BD); loadCol(j + 7, BD);
        }
    }

    // ---- b2 contribution: extra K-step with h == 1 (A-fragment = xs, no VALU) ----
#pragma unroll
    for (int ih = 0; ih < 2; ++ih) {
        f16x8 bfr = *(const f16x8*)(b2p + (ih * 64 + lane) * 8);
#pragma unroll
        for (int g = 0; g < 4; ++g) {
            u8h A;
#pragma unroll
            for (int p = 0; p < 4; ++p) A.h2[p] = xs[g][ih * 4 + p];
            acc[g] = __builtin_amdgcn_mfma_f32_32x32x16_f16(A.v, bfr, acc[g], 0, 0, 0);
        }
    }

    // ---- scatter-add directly into out (base already written by launch 1) ----
    if (live) {
#pragma unroll
        for (int g = 0; g < 4; ++g)
#pragma unroll
            for (int i = 0; i < 16; ++i) {
                int el = (i & 3) + ((i >> 2) << 3) + (half << 2);
                atomicAdd(out + (size_t)ei[EE + ebw + g * 32 + el] * 32 + l, acc[g][i]);
            }
    }
}

extern "C" void kernel_launch(void* const* d_in, const int* in_sizes, int n_in,
                              void* d_out, int out_size, void* d_ws, size_t ws_size,
                              hipStream_t stream) {
    const float* x    = (const float*)d_in[0];
    const int*   ei   = (const int*)  d_in[1];
    const float* ea   = (const float*)d_in[2];
    const float* w1   = (const float*)d_in[3];
    const float* b1   = (const float*)d_in[4];
    const float* w2   = (const float*)d_in[5];
    const float* b2   = (const float*)d_in[6];
    const float* root = (const float*)d_in[7];
    const float* bias = (const float*)d_in[8];
    float* out = (float*)d_out;

    _Float16* w2p = (_Float16*)d_ws;                      // 262144 B
    _Float16* w1p = (_Float16*)((char*)d_ws + 262144);    //   8192 B
    _Float16* b2p = (_Float16*)((char*)d_ws + 270336);    //   2048 B

    // launch 1: pack + base output (800000 threads exactly)
    prep_final_kernel<<<(NN * 32) / 256, 256, 0, stream>>>(
        x, root, bias, w1, w2, b2, w2p, w1p, b2p, out);

    // launch 2: edge compute + atomic scatter into out
    edge_kernel<<<(EE + 255) / 256, 128, 0, stream>>>(
        x, ei, ea, b1, w2p, w1p, b2p, out);
}